// Round 13
// baseline (284.216 us; speedup 1.0000x reference)
//
#include <hip/hip_runtime.h>

#define DMODEL 256
#define DCH 128
#define LN_EPS 1e-5f
#define SROW (DMODEL + 8)  // +16B pad: LDS row stride 528B -> max 2-way bank conflict (free)

typedef float f32x4 __attribute__((ext_vector_type(4)));
typedef short s16x8 __attribute__((ext_vector_type(8)));

__device__ __forceinline__ unsigned short f2bf(float f) {
  unsigned int u = __float_as_uint(f);
  unsigned int r = (u + 0x7FFF + ((u >> 16) & 1)) >> 16;  // RNE
  return (unsigned short)r;
}
__device__ __forceinline__ unsigned int pk2bf(float x, float y) {
  return ((unsigned int)f2bf(y) << 16) | f2bf(x);
}
__device__ __forceinline__ float bflo(unsigned int u) { return __uint_as_float(u << 16); }
__device__ __forceinline__ float bfhi(unsigned int u) { return __uint_as_float(u & 0xFFFF0000u); }

// ---------------- CSR hist + bf16 conversions (x, Wc, Wp) ----------------
__global__ __launch_bounds__(256) void hist_cvt_kernel(
    const int* __restrict__ row, const int* __restrict__ col,
    int* cnt_row, int* cnt_col, int E,
    const float* __restrict__ x, unsigned short* __restrict__ xbf, int nx8,
    const float* __restrict__ Wc, unsigned short* __restrict__ Wcb,
    const float* __restrict__ Wp, unsigned short* __restrict__ Wpb, int nw8) {
  int tid = blockIdx.x * 256 + threadIdx.x;
  if (tid < E) {
    atomicAdd(&cnt_row[row[tid]], 1);
    atomicAdd(&cnt_col[col[tid]], 1);
  }
  if (tid < nx8) {
    float4 a = *(const float4*)&x[tid * 8];
    float4 b = *(const float4*)&x[tid * 8 + 4];
    uint4 o = {pk2bf(a.x, a.y), pk2bf(a.z, a.w), pk2bf(b.x, b.y), pk2bf(b.z, b.w)};
    *(uint4*)&xbf[tid * 8] = o;
  }
  if (tid < nw8) {
    float4 a = *(const float4*)&Wc[tid * 8];
    float4 b = *(const float4*)&Wc[tid * 8 + 4];
    uint4 o = {pk2bf(a.x, a.y), pk2bf(a.z, a.w), pk2bf(b.x, b.y), pk2bf(b.z, b.w)};
    *(uint4*)&Wcb[tid * 8] = o;
    a = *(const float4*)&Wp[tid * 8];
    b = *(const float4*)&Wp[tid * 8 + 4];
    uint4 o2 = {pk2bf(a.x, a.y), pk2bf(a.z, a.w), pk2bf(b.x, b.y), pk2bf(b.z, b.w)};
    *(uint4*)&Wpb[tid * 8] = o2;
  }
}

// ---------------- scan + dis (one block) ----------------
__global__ __launch_bounds__(256) void scan_dis_kernel(
    const int* __restrict__ cnt_col, const int* __restrict__ cnt_row,
    int* __restrict__ indptr, int* __restrict__ cursor,
    float* __restrict__ dis, int N, int E) {
  int t = threadIdx.x;
  for (int i = t; i < N; i += 256) dis[i] = rsqrtf((float)(cnt_row[i] + 1));
  const int PER = (N + 255) / 256;
  int start = t * PER;
  int sum = 0;
  for (int k = 0; k < PER; ++k) {
    int i = start + k;
    if (i < N) sum += cnt_col[i];
  }
  int lane = t & 63, wid = t >> 6;
  int inc = sum;
#pragma unroll
  for (int off = 1; off < 64; off <<= 1) {
    int v = __shfl_up(inc, off);
    if (lane >= off) inc += v;
  }
  __shared__ int wsum[4];
  if (lane == 63) wsum[wid] = inc;
  __syncthreads();
  int woff = 0;
  for (int w = 0; w < wid; ++w) woff += wsum[w];
  int run = woff + inc - sum;
  for (int k = 0; k < PER; ++k) {
    int i = start + k;
    if (i < N) {
      indptr[i] = run;
      cursor[i] = run;
      run += cnt_col[i];
    }
  }
  if (t == 255) indptr[N] = E;
}

__global__ __launch_bounds__(256) void fill_kernel(const int* __restrict__ row,
    const int* __restrict__ col, int* cursor, int* __restrict__ idx, int E) {
  int e = blockIdx.x * 256 + threadIdx.x;
  if (e < E) {
    int pos = atomicAdd(&cursor[col[e]], 1);
    idx[pos] = row[e];
  }
}

// ---------------- fused layer: aggregate (LDS) -> MFMA xform -> LN -> residual ----------------
// 512 threads = 8 waves; 32 output rows per block.
// Phase 1: wave w aggregates rows w*4..w*4+3 into S_lds (bf16) + swt_lds.
// Phase 2: MFMA 32x256 = S @ [Wc|Wp]^T + bias*swt; LN+ReLU+residual; store fp32 + bf16.
// MFMA frag layouts verified on HW (R7): A/B row|col=lane&15, k=(lane>>4)*8+j; D col=lane&15, row=(lane>>4)*4+j.
__global__ __launch_bounds__(512) void layer_kernel(
    const unsigned short* __restrict__ xbf, const float* __restrict__ xres,
    const unsigned short* __restrict__ Wcb, const unsigned short* __restrict__ Wpb,
    const float* __restrict__ bc, const float* __restrict__ bp,
    const float* __restrict__ gamma, const float* __restrict__ beta,
    const float* __restrict__ dis, const int* __restrict__ indptr,
    const int* __restrict__ idx, const int* __restrict__ noi,
    float* __restrict__ xout, unsigned short* __restrict__ xbf_out,
    int use_noi, int relu, int R) {
  __shared__ unsigned short S_lds[32][SROW];
  __shared__ float swt_lds[32];
  __shared__ float red1[32][4], red2[32][4], muS[32], rsS[32];

  int t = threadIdx.x;
  int w = t >> 6, lane = t & 63;
  int r0 = blockIdx.x * 32;

  // ---- phase 1: aggregation
  for (int q = 0; q < 4; ++q) {
    int lr = w * 4 + q;
    int r = r0 + lr;
    if (r < R) {
      int i = use_noi ? noi[r] : r;
      float di = dis[i];
      float di2 = di * di;
      uint2 u = *(const uint2*)(xbf + (size_t)i * DMODEL + lane * 4);
      float a0 = di2 * bflo(u.x), a1 = di2 * bfhi(u.x);
      float a2 = di2 * bflo(u.y), a3 = di2 * bfhi(u.y);
      int s = indptr[i], e = indptr[i + 1];
      float sw = 0.f;
      for (int base = s; base < e; base += 64) {
        int n = min(64, e - base);
        int sr = 0;
        float wt = 0.f;
        if (lane < n) {
          sr = idx[base + lane];
          wt = dis[sr] * di;
        }
        int j = 0;
        for (; j + 4 <= n; j += 4) {
          int s0 = __shfl(sr, j), s1 = __shfl(sr, j + 1), s2 = __shfl(sr, j + 2), s3 = __shfl(sr, j + 3);
          float w0 = __shfl(wt, j), w1 = __shfl(wt, j + 1), w2 = __shfl(wt, j + 2), w3 = __shfl(wt, j + 3);
          uint2 u0 = *(const uint2*)(xbf + (size_t)s0 * DMODEL + lane * 4);
          uint2 u1 = *(const uint2*)(xbf + (size_t)s1 * DMODEL + lane * 4);
          uint2 u2 = *(const uint2*)(xbf + (size_t)s2 * DMODEL + lane * 4);
          uint2 u3 = *(const uint2*)(xbf + (size_t)s3 * DMODEL + lane * 4);
          a0 += w0 * bflo(u0.x); a1 += w0 * bfhi(u0.x); a2 += w0 * bflo(u0.y); a3 += w0 * bfhi(u0.y);
          a0 += w1 * bflo(u1.x); a1 += w1 * bfhi(u1.x); a2 += w1 * bflo(u1.y); a3 += w1 * bfhi(u1.y);
          a0 += w2 * bflo(u2.x); a1 += w2 * bfhi(u2.x); a2 += w2 * bflo(u2.y); a3 += w2 * bfhi(u2.y);
          a0 += w3 * bflo(u3.x); a1 += w3 * bfhi(u3.x); a2 += w3 * bflo(u3.y); a3 += w3 * bfhi(u3.y);
          sw += w0 + w1 + w2 + w3;
        }
        for (; j < n; ++j) {
          int sj_ = __shfl(sr, j);
          float wj = __shfl(wt, j);
          uint2 uu = *(const uint2*)(xbf + (size_t)sj_ * DMODEL + lane * 4);
          a0 += wj * bflo(uu.x); a1 += wj * bfhi(uu.x); a2 += wj * bflo(uu.y); a3 += wj * bfhi(uu.y);
          sw += wj;
        }
      }
      *(uint2*)&S_lds[lr][lane * 4] = (uint2){pk2bf(a0, a1), pk2bf(a2, a3)};
      if (lane == 0) swt_lds[lr] = di2 + sw;
    } else {
      *(uint2*)&S_lds[lr][lane * 4] = (uint2){0u, 0u};
      if (lane == 0) swt_lds[lr] = 0.f;
    }
  }
  __syncthreads();

  // ---- phase 2: MFMA transform
  int mt = w & 1, cq = w >> 1;    // cq 0..3 over 256 cols
  int h = cq >> 1, cgg = cq & 1;  // half (content/position), 64-col group
  int lrow = lane & 15, kgrp = lane >> 4;

  int orow0 = mt * 16 + kgrp * 4;
  float sj[4];
#pragma unroll
  for (int j = 0; j < 4; ++j) sj[j] = swt_lds[orow0 + j];

  const unsigned short* Wh = h ? Wpb : Wcb;
  const float* bh = h ? bp : bc;

  int colw[4];
  const unsigned short* bpw[4];
  f32x4 acc[4];
#pragma unroll
  for (int nt = 0; nt < 4; ++nt) {
    colw[nt] = cgg * 64 + nt * 16 + lrow;
    bpw[nt] = Wh + (size_t)colw[nt] * DCH + kgrp * 8;
    float bias = bh[colw[nt]];
    acc[nt] = (f32x4){bias * sj[0], bias * sj[1], bias * sj[2], bias * sj[3]};
  }

  const unsigned short* ap = &S_lds[mt * 16 + lrow][h * DCH + kgrp * 8];

  union U8 { s16x8 v; uint4 q; };
#pragma unroll
  for (int kt = 0; kt < 4; ++kt) {
    U8 af;
    af.q = *(const uint4*)(ap + kt * 32);
#pragma unroll
    for (int nt = 0; nt < 4; ++nt) {
      U8 bf;
      bf.q = *(const uint4*)(bpw[nt] + kt * 32);
      acc[nt] = __builtin_amdgcn_mfma_f32_16x16x32_bf16(af.v, bf.v, acc[nt], 0, 0, 0);
    }
  }

  // ---- LN reduction (verified structure from R8)
  float p1[4], p2[4];
#pragma unroll
  for (int j = 0; j < 4; ++j) {
    p1[j] = acc[0][j] + acc[1][j] + acc[2][j] + acc[3][j];
    p2[j] = acc[0][j] * acc[0][j] + acc[1][j] * acc[1][j] +
            acc[2][j] * acc[2][j] + acc[3][j] * acc[3][j];
  }
#pragma unroll
  for (int off = 8; off > 0; off >>= 1) {
#pragma unroll
    for (int j = 0; j < 4; ++j) {
      p1[j] += __shfl_down(p1[j], off, 16);
      p2[j] += __shfl_down(p2[j], off, 16);
    }
  }
  if (lrow == 0) {
#pragma unroll
    for (int j = 0; j < 4; ++j) {
      red1[orow0 + j][cq] = p1[j];
      red2[orow0 + j][cq] = p2[j];
    }
  }
  __syncthreads();
  if (t < 32) {
    float s1 = red1[t][0] + red1[t][1] + red1[t][2] + red1[t][3];
    float s2 = red2[t][0] + red2[t][1] + red2[t][2] + red2[t][3];
    float mu = s1 * (1.0f / DMODEL);
    float var = s2 * (1.0f / DMODEL) - mu * mu;
    muS[t] = mu;
    rsS[t] = rsqrtf(var + LN_EPS);
  }
  __syncthreads();

#pragma unroll
  for (int nt = 0; nt < 4; ++nt) {
    int col = h * DCH + colw[nt];
    float g = gamma[col], bt = beta[col];
#pragma unroll
    for (int j = 0; j < 4; ++j) {
      int rr = orow0 + j;
      int grow = r0 + rr;
      if (grow < R) {
        float y = (acc[nt][j] - muS[rr]) * rsS[rr] * g + bt;
        if (relu) y = fmaxf(y, 0.f);
        int node = use_noi ? noi[grow] : grow;
        float o = xres[(size_t)node * DMODEL + col] + y;
        xout[(size_t)grow * DMODEL + col] = o;
        if (xbf_out) xbf_out[(size_t)grow * DMODEL + col] = f2bf(o);
      }
    }
  }
}

extern "C" void kernel_launch(void* const* d_in, const int* in_sizes, int n_in,
                              void* d_out, int out_size, void* d_ws, size_t ws_size,
                              hipStream_t stream) {
  const float* x     = (const float*)d_in[0];
  const int*   edges = (const int*)d_in[1];
  const int*   noi   = (const int*)d_in[2];
  const float* Wc    = (const float*)d_in[3];
  const float* bc    = (const float*)d_in[4];
  const float* Wp    = (const float*)d_in[5];
  const float* bp    = (const float*)d_in[6];
  const float* gamma = (const float*)d_in[7];
  const float* beta  = (const float*)d_in[8];

  int N = in_sizes[0] / DMODEL;
  int E = in_sizes[1] / 2;
  int K = in_sizes[2];
  int nwElem = in_sizes[3];  // L*DC*DC
  const int* row = edges;
  const int* col = edges + E;

  char* base = (char*)d_ws;
  size_t off = 0;
  auto alloc = [&](size_t bytes) -> void* {
    void* p = base + off;
    off += (bytes + 255) & ~(size_t)255;
    return p;
  };

  unsigned short* xbf0   = (unsigned short*)alloc((size_t)N * DMODEL * 2);
  unsigned short* xbfA   = (unsigned short*)alloc((size_t)N * DMODEL * 2);
  unsigned short* xbfB   = (unsigned short*)alloc((size_t)N * DMODEL * 2);
  float*          xA     = (float*)alloc((size_t)N * DMODEL * 4);
  float*          xB     = (float*)alloc((size_t)N * DMODEL * 4);
  unsigned short* Wcb    = (unsigned short*)alloc((size_t)nwElem * 2);
  unsigned short* Wpb    = (unsigned short*)alloc((size_t)nwElem * 2);
  float*          dis    = (float*)alloc((size_t)N * 4);
  int*            cnt    = (int*)alloc((size_t)2 * N * 4);
  int*            indptr = (int*)alloc((size_t)(N + 1) * 4);
  int*            cursor = (int*)alloc((size_t)N * 4);
  int*            idx    = (int*)alloc((size_t)E * 4);

  hipMemsetAsync(cnt, 0, (size_t)2 * N * 4, stream);

  int nx8 = (N * DMODEL) / 8;
  int nw8 = nwElem / 8;
  int mx = E > nx8 ? E : nx8;
  if (nw8 > mx) mx = nw8;
  hist_cvt_kernel<<<(mx + 255) / 256, 256, 0, stream>>>(
      row, col, cnt, cnt + N, E, x, xbf0, nx8, Wc, Wcb, Wp, Wpb, nw8);
  scan_dis_kernel<<<1, 256, 0, stream>>>(cnt + N, cnt, indptr, cursor, dis, N, E);
  fill_kernel<<<(E + 255) / 256, 256, 0, stream>>>(row, col, cursor, idx, E);

  size_t wl = (size_t)DCH * DCH;
  // layer 0
  layer_kernel<<<(N + 31) / 32, 512, 0, stream>>>(
      xbf0, x, Wcb, Wpb, bc, bp, gamma, beta, dis, indptr, idx, nullptr,
      xA, xbfA, 0, 1, N);
  // layer 1
  layer_kernel<<<(N + 31) / 32, 512, 0, stream>>>(
      xbfA, xA, Wcb + wl, Wpb + wl, bc + DCH, bp + DCH,
      gamma + DMODEL, beta + DMODEL, dis, indptr, idx, nullptr,
      xB, xbfB, 0, 1, N);
  // layer 2: only noi rows, write d_out
  layer_kernel<<<(K + 31) / 32, 512, 0, stream>>>(
      xbfB, xB, Wcb + 2 * wl, Wpb + 2 * wl, bc + 2 * DCH, bp + 2 * DCH,
      gamma + 2 * DMODEL, beta + 2 * DMODEL, dis, indptr, idx, noi,
      (float*)d_out, nullptr, 1, 0, K);
}

// Round 14
// 239.340 us; speedup vs baseline: 1.1875x; 1.1875x over previous
//
#include <hip/hip_runtime.h>

#define DMODEL 256
#define DCH 128
#define LN_EPS 1e-5f

typedef float f32x4 __attribute__((ext_vector_type(4)));
typedef short s16x8 __attribute__((ext_vector_type(8)));

__device__ __forceinline__ unsigned short f2bf(float f) {
  unsigned int u = __float_as_uint(f);
  unsigned int r = (u + 0x7FFF + ((u >> 16) & 1)) >> 16;  // RNE
  return (unsigned short)r;
}
__device__ __forceinline__ unsigned int pk2bf(float x, float y) {
  return ((unsigned int)f2bf(y) << 16) | f2bf(x);
}
__device__ __forceinline__ float bflo(unsigned int u) { return __uint_as_float(u << 16); }
__device__ __forceinline__ float bfhi(unsigned int u) { return __uint_as_float(u & 0xFFFF0000u); }

// ---------------- CSR hist + bf16 conversions (x, Wc, Wp) ----------------
__global__ __launch_bounds__(256) void hist_cvt_kernel(
    const int* __restrict__ row, const int* __restrict__ col,
    int* cnt_row, int* cnt_col, int E,
    const float* __restrict__ x, unsigned short* __restrict__ xbf, int nx8,
    const float* __restrict__ Wc, unsigned short* __restrict__ Wcb,
    const float* __restrict__ Wp, unsigned short* __restrict__ Wpb, int nw8) {
  int tid = blockIdx.x * 256 + threadIdx.x;
  if (tid < E) {
    atomicAdd(&cnt_row[row[tid]], 1);
    atomicAdd(&cnt_col[col[tid]], 1);
  }
  if (tid < nx8) {
    float4 a = *(const float4*)&x[tid * 8];
    float4 b = *(const float4*)&x[tid * 8 + 4];
    uint4 o = {pk2bf(a.x, a.y), pk2bf(a.z, a.w), pk2bf(b.x, b.y), pk2bf(b.z, b.w)};
    *(uint4*)&xbf[tid * 8] = o;
  }
  if (tid < nw8) {
    float4 a = *(const float4*)&Wc[tid * 8];
    float4 b = *(const float4*)&Wc[tid * 8 + 4];
    uint4 o = {pk2bf(a.x, a.y), pk2bf(a.z, a.w), pk2bf(b.x, b.y), pk2bf(b.z, b.w)};
    *(uint4*)&Wcb[tid * 8] = o;
    a = *(const float4*)&Wp[tid * 8];
    b = *(const float4*)&Wp[tid * 8 + 4];
    uint4 o2 = {pk2bf(a.x, a.y), pk2bf(a.z, a.w), pk2bf(b.x, b.y), pk2bf(b.z, b.w)};
    *(uint4*)&Wpb[tid * 8] = o2;
  }
}

// ---------------- scan + dis (one 1024-thread block; PER=10 serial) ----------------
__global__ __launch_bounds__(1024) void scan_dis_kernel(
    const int* __restrict__ cnt_col, const int* __restrict__ cnt_row,
    int* __restrict__ indptr, int* __restrict__ cursor,
    float* __restrict__ dis, int N, int E) {
  int t = threadIdx.x;
  for (int i = t; i < N; i += 1024) dis[i] = rsqrtf((float)(cnt_row[i] + 1));

  const int PER = (N + 1023) / 1024;  // rounded up; chunk loads below handle tail
  int start = t * PER;
  int c[16];  // PER <= 16 for N <= 16384
  int sum = 0;
  for (int k = 0; k < PER; ++k) {
    int i = start + k;
    c[k] = (i < N) ? cnt_col[i] : 0;
    sum += c[k];
  }
  int lane = t & 63, wid = t >> 6;
  int inc = sum;
#pragma unroll
  for (int off = 1; off < 64; off <<= 1) {
    int v = __shfl_up(inc, off);
    if (lane >= off) inc += v;
  }
  __shared__ int wsum[16];
  if (lane == 63) wsum[wid] = inc;
  __syncthreads();
  int woff = 0;
  for (int w = 0; w < wid; ++w) woff += wsum[w];
  int run = woff + inc - sum;  // exclusive prefix for this thread's chunk
  for (int k = 0; k < PER; ++k) {
    int i = start + k;
    if (i < N) {
      indptr[i] = run;
      cursor[i] = run;
      run += c[k];
    }
  }
  if (t == 1023) indptr[N] = E;
}

__global__ __launch_bounds__(256) void fill_kernel(const int* __restrict__ row,
    const int* __restrict__ col, int* cursor, int* __restrict__ idx, int E) {
  int e = blockIdx.x * 256 + threadIdx.x;
  if (e < E) {
    int pos = atomicAdd(&cursor[col[e]], 1);
    idx[pos] = row[e];
  }
}

// ---------------- aggregation: S[r] = sum_e norm_e * xbf[row_e], swt[r] = sum_e norm_e ----------------
// wave per output row; lane owns dims lane*4..+3. No LDS, no barriers (shfl broadcast).
__global__ __launch_bounds__(256) void agg_kernel(
    const unsigned short* __restrict__ xbf, unsigned short* __restrict__ S,
    float* __restrict__ swt, const float* __restrict__ dis,
    const int* __restrict__ indptr, const int* __restrict__ idx,
    const int* __restrict__ noi, int use_noi, int R) {
  int wave = threadIdx.x >> 6, lane = threadIdx.x & 63;
  int r = blockIdx.x * 4 + wave;
  int rc = min(r, R - 1);
  int i = use_noi ? noi[rc] : rc;
  float di = dis[i];
  float di2 = di * di;

  uint2 u = *(const uint2*)(xbf + (size_t)i * DMODEL + lane * 4);
  float a0 = di2 * bflo(u.x), a1 = di2 * bfhi(u.x);
  float a2 = di2 * bflo(u.y), a3 = di2 * bfhi(u.y);

  int s = indptr[i], e = indptr[i + 1];
  float sw = 0.f;
  for (int base = s; base < e; base += 64) {
    int n = min(64, e - base);
    int sr = 0;
    float w = 0.f;
    if (lane < n) {
      sr = idx[base + lane];
      w = dis[sr] * di;
    }
    int j = 0;
    for (; j + 4 <= n; j += 4) {
      int s0 = __shfl(sr, j), s1 = __shfl(sr, j + 1), s2 = __shfl(sr, j + 2), s3 = __shfl(sr, j + 3);
      float w0 = __shfl(w, j), w1 = __shfl(w, j + 1), w2 = __shfl(w, j + 2), w3 = __shfl(w, j + 3);
      uint2 u0 = *(const uint2*)(xbf + (size_t)s0 * DMODEL + lane * 4);
      uint2 u1 = *(const uint2*)(xbf + (size_t)s1 * DMODEL + lane * 4);
      uint2 u2 = *(const uint2*)(xbf + (size_t)s2 * DMODEL + lane * 4);
      uint2 u3 = *(const uint2*)(xbf + (size_t)s3 * DMODEL + lane * 4);
      a0 += w0 * bflo(u0.x); a1 += w0 * bfhi(u0.x); a2 += w0 * bflo(u0.y); a3 += w0 * bfhi(u0.y);
      a0 += w1 * bflo(u1.x); a1 += w1 * bfhi(u1.x); a2 += w1 * bflo(u1.y); a3 += w1 * bfhi(u1.y);
      a0 += w2 * bflo(u2.x); a1 += w2 * bfhi(u2.x); a2 += w2 * bflo(u2.y); a3 += w2 * bfhi(u2.y);
      a0 += w3 * bflo(u3.x); a1 += w3 * bfhi(u3.x); a2 += w3 * bflo(u3.y); a3 += w3 * bfhi(u3.y);
      sw += w0 + w1 + w2 + w3;
    }
    for (; j < n; ++j) {
      int sj = __shfl(sr, j);
      float wj = __shfl(w, j);
      uint2 uu = *(const uint2*)(xbf + (size_t)sj * DMODEL + lane * 4);
      a0 += wj * bflo(uu.x); a1 += wj * bfhi(uu.x); a2 += wj * bflo(uu.y); a3 += wj * bfhi(uu.y);
      sw += wj;
    }
  }
  if (r < R) {
    uint2 o = {pk2bf(a0, a1), pk2bf(a2, a3)};
    *(uint2*)(S + (size_t)r * DMODEL + lane * 4) = o;
    if (lane == 0) swt[r] = di2 + sw;
  }
}

// ---------------- fused transform: z = [Wc Sc + bc*s, Wp Sp + bp*s]; out = xin + [relu]LN(z) ----------------
// 512 threads = 8 waves; 32 rows/block.
// A/B frag layout verified on HW (R7): row|col = lane&15, k = (lane>>4)*8 + j; D: col=lane&15,row=(lane>>4)*4+j.
__global__ __launch_bounds__(512) void xform_kernel(
    const unsigned short* __restrict__ S, const float* __restrict__ swt,
    const unsigned short* __restrict__ Wcb, const unsigned short* __restrict__ Wpb,
    const float* __restrict__ bc, const float* __restrict__ bp,
    const float* __restrict__ gamma, const float* __restrict__ beta,
    const float* __restrict__ xin, const int* __restrict__ noi,
    float* __restrict__ xout, unsigned short* __restrict__ xbf_out,
    int use_noi, int relu, int R) {
  int t = threadIdx.x;
  int w = t >> 6, lane = t & 63;
  int mt = w & 1, cq = w >> 1;       // cq 0..3 over 256 cols
  int h = cq >> 1, cgg = cq & 1;     // half (c/p), 64-col group within half
  int lrow = lane & 15, kgrp = lane >> 4;
  int r0 = blockIdx.x * 32;

  int arow = r0 + mt * 16 + lrow;
  int arow_c = min(arow, R - 1);
  const unsigned short* ap = S + (size_t)arow_c * DMODEL + h * DCH + kgrp * 8;
  const unsigned short* Wh = h ? Wpb : Wcb;
  const float* bh = h ? bp : bc;

  int orow0 = mt * 16 + kgrp * 4;  // local row of acc element j
  float sj[4];
#pragma unroll
  for (int j = 0; j < 4; ++j) sj[j] = swt[min(r0 + orow0 + j, R - 1)];

  int colw[4];
  const unsigned short* bpw[4];
  f32x4 acc[4];
#pragma unroll
  for (int nt = 0; nt < 4; ++nt) {
    colw[nt] = cgg * 64 + nt * 16 + lrow;
    bpw[nt] = Wh + (size_t)colw[nt] * DCH + kgrp * 8;
    float bias = bh[colw[nt]];
    acc[nt] = (f32x4){bias * sj[0], bias * sj[1], bias * sj[2], bias * sj[3]};
  }

  union U8 { s16x8 v; uint4 q; };
#pragma unroll
  for (int kt = 0; kt < 4; ++kt) {
    U8 af;
    af.q = *(const uint4*)(ap + kt * 32);
#pragma unroll
    for (int nt = 0; nt < 4; ++nt) {
      U8 bf;
      bf.q = *(const uint4*)(bpw[nt] + kt * 32);
      acc[nt] = __builtin_amdgcn_mfma_f32_16x16x32_bf16(af.v, bf.v, acc[nt], 0, 0, 0);
    }
  }

  // LN partial sums: per lane, over its 4 cols, for each of its 4 rows
  float p1[4], p2[4];
#pragma unroll
  for (int j = 0; j < 4; ++j) {
    p1[j] = acc[0][j] + acc[1][j] + acc[2][j] + acc[3][j];
    p2[j] = acc[0][j] * acc[0][j] + acc[1][j] * acc[1][j] +
            acc[2][j] * acc[2][j] + acc[3][j] * acc[3][j];
  }
#pragma unroll
  for (int off = 8; off > 0; off >>= 1) {
#pragma unroll
    for (int j = 0; j < 4; ++j) {
      p1[j] += __shfl_down(p1[j], off, 16);
      p2[j] += __shfl_down(p2[j], off, 16);
    }
  }
  __shared__ float red1[32][4], red2[32][4];
  __shared__ float muS[32], rsS[32];
  if (lrow == 0) {
#pragma unroll
    for (int j = 0; j < 4; ++j) {
      red1[orow0 + j][cq] = p1[j];
      red2[orow0 + j][cq] = p2[j];
    }
  }
  __syncthreads();
  if (t < 32) {
    float s1 = red1[t][0] + red1[t][1] + red1[t][2] + red1[t][3];
    float s2 = red2[t][0] + red2[t][1] + red2[t][2] + red2[t][3];
    float mu = s1 * (1.0f / DMODEL);
    float var = s2 * (1.0f / DMODEL) - mu * mu;
    muS[t] = mu;
    rsS[t] = rsqrtf(var + LN_EPS);
  }
  __syncthreads();

#pragma unroll
  for (int nt = 0; nt < 4; ++nt) {
    int col = h * DCH + colw[nt];
    float g = gamma[col], bt = beta[col];
#pragma unroll
    for (int j = 0; j < 4; ++j) {
      int rr = orow0 + j;
      int grow = r0 + rr;
      if (grow < R) {
        float y = (acc[nt][j] - muS[rr]) * rsS[rr] * g + bt;
        if (relu) y = fmaxf(y, 0.f);
        int node = use_noi ? noi[grow] : grow;
        float o = xin[(size_t)node * DMODEL + col] + y;
        xout[(size_t)grow * DMODEL + col] = o;
        if (xbf_out) xbf_out[(size_t)grow * DMODEL + col] = f2bf(o);
      }
    }
  }
}

extern "C" void kernel_launch(void* const* d_in, const int* in_sizes, int n_in,
                              void* d_out, int out_size, void* d_ws, size_t ws_size,
                              hipStream_t stream) {
  const float* x     = (const float*)d_in[0];
  const int*   edges = (const int*)d_in[1];
  const int*   noi   = (const int*)d_in[2];
  const float* Wc    = (const float*)d_in[3];
  const float* bc    = (const float*)d_in[4];
  const float* Wp    = (const float*)d_in[5];
  const float* bp    = (const float*)d_in[6];
  const float* gamma = (const float*)d_in[7];
  const float* beta  = (const float*)d_in[8];

  int N = in_sizes[0] / DMODEL;
  int E = in_sizes[1] / 2;
  int K = in_sizes[2];
  int nwElem = in_sizes[3];  // L*DC*DC
  const int* row = edges;
  const int* col = edges + E;

  char* base = (char*)d_ws;
  size_t off = 0;
  auto alloc = [&](size_t bytes) -> void* {
    void* p = base + off;
    off += (bytes + 255) & ~(size_t)255;
    return p;
  };

  unsigned short* xbf0   = (unsigned short*)alloc((size_t)N * DMODEL * 2);
  unsigned short* xbfA   = (unsigned short*)alloc((size_t)N * DMODEL * 2);
  unsigned short* xbfB   = (unsigned short*)alloc((size_t)N * DMODEL * 2);
  unsigned short* Sb     = (unsigned short*)alloc((size_t)N * DMODEL * 2);
  float*          xA     = (float*)alloc((size_t)N * DMODEL * 4);
  float*          xB     = (float*)alloc((size_t)N * DMODEL * 4);
  unsigned short* Wcb    = (unsigned short*)alloc((size_t)nwElem * 2);
  unsigned short* Wpb    = (unsigned short*)alloc((size_t)nwElem * 2);
  float*          swt    = (float*)alloc((size_t)N * 4);
  float*          dis    = (float*)alloc((size_t)N * 4);
  int*            cnt    = (int*)alloc((size_t)2 * N * 4);
  int*            indptr = (int*)alloc((size_t)(N + 1) * 4);
  int*            cursor = (int*)alloc((size_t)N * 4);
  int*            idx    = (int*)alloc((size_t)E * 4);

  hipMemsetAsync(cnt, 0, (size_t)2 * N * 4, stream);

  int nx8 = (N * DMODEL) / 8;
  int nw8 = nwElem / 8;
  int mx = E > nx8 ? E : nx8;
  if (nw8 > mx) mx = nw8;
  hist_cvt_kernel<<<(mx + 255) / 256, 256, 0, stream>>>(
      row, col, cnt, cnt + N, E, x, xbf0, nx8, Wc, Wcb, Wp, Wpb, nw8);
  scan_dis_kernel<<<1, 1024, 0, stream>>>(cnt + N, cnt, indptr, cursor, dis, N, E);
  fill_kernel<<<(E + 255) / 256, 256, 0, stream>>>(row, col, cursor, idx, E);

  size_t wl = (size_t)DCH * DCH;
  // layer 0
  agg_kernel<<<(N + 3) / 4, 256, 0, stream>>>(xbf0, Sb, swt, dis, indptr, idx, nullptr, 0, N);
  xform_kernel<<<(N + 31) / 32, 512, 0, stream>>>(
      Sb, swt, Wcb, Wpb, bc, bp, gamma, beta, x, nullptr, xA, xbfA, 0, 1, N);
  // layer 1
  agg_kernel<<<(N + 3) / 4, 256, 0, stream>>>(xbfA, Sb, swt, dis, indptr, idx, nullptr, 0, N);
  xform_kernel<<<(N + 31) / 32, 512, 0, stream>>>(
      Sb, swt, Wcb + wl, Wpb + wl, bc + DCH, bp + DCH,
      gamma + DMODEL, beta + DMODEL, xA, nullptr, xB, xbfB, 0, 1, N);
  // layer 2 (only noi rows)
  agg_kernel<<<(K + 3) / 4, 256, 0, stream>>>(xbfB, Sb, swt, dis, indptr, idx, noi, 1, K);
  xform_kernel<<<(K + 31) / 32, 512, 0, stream>>>(
      Sb, swt, Wcb + 2 * wl, Wpb + 2 * wl, bc + 2 * DCH, bp + 2 * DCH,
      gamma + 2 * DMODEL, beta + 2 * DMODEL, xB, noi, (float*)d_out, nullptr, 1, 0, K);
}